// Round 13
// baseline (134.009 us; speedup 1.0000x reference)
//
#include <hip/hip_runtime.h>

// Trilinear forward-splat, corner-basis LDS accumulation (2 DS atomics/voxel),
// double-buffered chunk-pair pipeline with wave-role split.
// R12->R13: phases were lockstep-serialized at CU level (DS floor 59us + VALU
// 47us ~= measured 123us; R4/R5/R9 invariances all consistent). Each block now
// processes TWO 8x8x32 chunks: P1 all-wave scatter chunk0->binsA; P2 waves 0-3
// scatter chunk1->binsB WHILE waves 4-7 flush binsA; P3 all flush binsB.
// DS pipe stays fed during flush; flush waves' lgkm FIFO has no atomics.
// Reference semantics (exact):
//   locs = max(grid + flow, 0)
//   delta = locs - floor(locs)           (from UNclamped floor)
//   base  = min((int)floor(locs), dim-1)
//   corner per axis = min(base + {0,1}, dim-1)   (collapsed corners add twice)
//
// Per x-corner deposit into bin (a,b0,c0), fields scale 2^9 fixed-point:
//   F_A=w(1-dy)(1-dz) -> cell(b0,c0);     F_B=w*dy(1-dz) -> cell(b0+1,c0)
//   F_C=w(1-dy)dz     -> cell(b0,c0+1);   F_D=w*dy*dz    -> cell(b0+1,c0+1)
// cell(b,z) = e0[bin(b,z)] + e1[bin(b-1,z)] + e2[bin(b,z-1)] + e3[bin(b-1,z-1)]

typedef unsigned long long u64;

constexpr int H = 192, W = 192, Dd = 192;
constexpr int N = H * W * Dd;
constexpr int WD = W * Dd;

constexpr int BI = 8, BJ = 8, BK = 32;       // per sub-chunk (block does 2 in z)
constexpr int HL = 2;
constexpr int TI = BI + 2 * HL;              // 12
constexpr int TJ = BJ + 2 * HL;              // 12
constexpr int TK = BK + 2 * HL;              // 36
constexpr int TJS = TJ - 1;                  // 11
constexpr int TKS = TK - 1;                  // 35
constexpr int TBINS = TI * TJS * TKS;        // 4620 u64 = 36.96 KB per buffer

constexpr float SCALE     = 512.0f;
constexpr float INV_SCALE = 1.0f / 512.0f;

__device__ __forceinline__ u64 pack4(float fa, float fb, float fc, float fd) {
    const int d0 = (int)rintf(fa * SCALE);
    const int d1 = (int)rintf(fb * SCALE);
    const int d2 = (int)rintf(fc * SCALE);
    const int d3 = (int)rintf(fd * SCALE);
    const int lo = d0 + (d1 << 16);
    const int hi = d2 + (d3 << 16) - (lo < 0 ? 1 : 0);
    return ((u64)(unsigned)hi << 32) | (unsigned)lo;
}

__device__ __forceinline__ int fld0(u64 T) {
    return (int)(short)(unsigned short)(unsigned)T;
}
__device__ __forceinline__ int fld1(u64 T) {
    const int lo = (int)(unsigned)T;
    return (lo - (int)(short)(unsigned short)lo) >> 16;
}
__device__ __forceinline__ int fld2(u64 T) {
    const int lo = (int)(unsigned)T;
    const int hi = (int)(unsigned)(T >> 32) + (lo < 0 ? 1 : 0);
    return (int)(short)(unsigned short)hi;
}
__device__ __forceinline__ int fld3(u64 T) {
    const int lo = (int)(unsigned)T;
    const int hi = (int)(unsigned)(T >> 32) + (lo < 0 ? 1 : 0);
    return (hi - (int)(short)(unsigned short)hi) >> 16;
}

// scatter 4 consecutive-z voxels (data in regs) into bins / outlier path
__device__ __forceinline__ void scatter4(const float4 s4, const float4 fx4,
                                         const float4 fy4, const float4 fz4,
                                         int i, int j, int k,
                                         int xg0, int yg0, int zg0,
                                         u64* bins, float* __restrict__ out) {
    const float sa[4]  = {s4.x, s4.y, s4.z, s4.w};
    const float fxa[4] = {fx4.x, fx4.y, fx4.z, fx4.w};
    const float fya[4] = {fy4.x, fy4.y, fy4.z, fy4.w};
    const float fza[4] = {fz4.x, fz4.y, fz4.z, fz4.w};

#pragma unroll
    for (int q = 0; q < 4; ++q) {
        const float lx = fmaxf((float)i       + fxa[q], 0.0f);
        const float ly = fmaxf((float)j       + fya[q], 0.0f);
        const float lz = fmaxf((float)(k + q) + fza[q], 0.0f);

        const float bx = floorf(lx), by = floorf(ly), bz = floorf(lz);
        const float dx = lx - bx,    dy = ly - by,    dz = lz - bz;

        const int x0 = min((int)bx, H - 1);
        const int y0 = min((int)by, W - 1);
        const int z0 = min((int)bz, Dd - 1);
        const int x1 = min(x0 + 1, H - 1);
        const int y1 = min(y0 + 1, W - 1);
        const int z1 = min(z0 + 1, Dd - 1);

        const float s = sa[q];
        const float dyf = (y1 > y0) ? dy : 0.0f;   // collapse -> full weight in clamped cell
        const float dzf = (z1 > z0) ? dz : 0.0f;

        const int a0 = x0 - xg0, a1 = x1 - xg0;
        const int b0 = y0 - yg0;
        const int c0 = z0 - zg0;

        const bool fast = ((unsigned)a0 < (unsigned)TI) & ((unsigned)a1 < (unsigned)TI) &
                          ((unsigned)b0 < (unsigned)TJS) &
                          ((unsigned)c0 < (unsigned)TKS);

        if (__builtin_expect(fast, 1)) {
            const float w0 = s * (1.0f - dx);
            const float w1 = s * dx;
            {
                const float m1 = w0 * dyf, m2 = w0 * dzf;
                const float FD = m1 * dzf;
                const float FB = m1 - FD, FC = m2 - FD;
                const float FA = (w0 - m1) - FC;
                atomicAdd(&bins[(a0 * TJS + b0) * TKS + c0], pack4(FA, FB, FC, FD));
            }
            {
                const float m1 = w1 * dyf, m2 = w1 * dzf;
                const float FD = m1 * dzf;
                const float FB = m1 - FD, FC = m2 - FD;
                const float FA = (w1 - m1) - FC;
                atomicAdd(&bins[(a1 * TJS + b0) * TKS + c0], pack4(FA, FB, FC, FD));
            }
        } else {
            const float wx0 = 1.0f - dx, wy0 = 1.0f - dy, wz0 = 1.0f - dz;
            const float a00 = s * wx0 * wy0;
            const float a01 = s * wx0 * dy;
            const float a10 = s * dx * wy0;
            const float a11 = s * dx * dy;
            unsafeAtomicAdd(out + x0 * WD + y0 * Dd + z0, a00 * wz0);
            unsafeAtomicAdd(out + x0 * WD + y0 * Dd + z1, a00 * dz);
            unsafeAtomicAdd(out + x0 * WD + y1 * Dd + z0, a01 * wz0);
            unsafeAtomicAdd(out + x0 * WD + y1 * Dd + z1, a01 * dz);
            unsafeAtomicAdd(out + x1 * WD + y0 * Dd + z0, a10 * wz0);
            unsafeAtomicAdd(out + x1 * WD + y0 * Dd + z1, a10 * dz);
            unsafeAtomicAdd(out + x1 * WD + y1 * Dd + z0, a11 * wz0);
            unsafeAtomicAdd(out + x1 * WD + y1 * Dd + z1, a11 * dz);
        }
    }
}

__device__ __forceinline__ void flush_bins(const u64* bins, float* __restrict__ out,
                                           int xg0, int yg0, int zg0,
                                           int start, int stride) {
    for (int c = start; c < TI * TJ * TK; c += stride) {
        const int z    = c % TK;
        const int rest = c / TK;
        const int b    = rest % TJ;
        const int a    = rest / TJ;

        const int rb = (a * TJS + b) * TKS;
        const int rm = rb - TKS;
        const bool hb = (b < TJS), hm = (b > 0);
        const bool hz = (z < TKS), hzm = (z > 0);

        const u64 Tb  = (hb && hz)  ? bins[rb + z]     : 0ull;
        const u64 Tm  = (hm && hz)  ? bins[rm + z]     : 0ull;
        const u64 Tbz = (hb && hzm) ? bins[rb + z - 1] : 0ull;
        const u64 Tmz = (hm && hzm) ? bins[rm + z - 1] : 0ull;

        if ((Tb | Tm | Tbz | Tmz) == 0ull) continue;

        const int vi = fld0(Tb) + fld1(Tm) + fld2(Tbz) + fld3(Tmz);
        if (vi != 0) {
            const int x = xg0 + a, y = yg0 + b, zz = zg0 + z;
            if (((unsigned)x < (unsigned)H) & ((unsigned)y < (unsigned)W) &
                ((unsigned)zz < (unsigned)Dd)) {
                unsafeAtomicAdd(out + x * WD + y * Dd + zz, (float)vi * INV_SCALE);
            }
        }
    }
}

__global__ __launch_bounds__(512, 4) void splat_pipe_kernel(const float* __restrict__ src,
                                                            const float* __restrict__ flow,
                                                            float* __restrict__ out) {
    __shared__ __align__(16) u64 bins[2][TBINS];   // 73.92 KB -> 2 blocks/CU

    const int t  = threadIdx.x;
    const int bk = blockIdx.x, bj = blockIdx.y, bi = blockIdx.z;
    const int i0 = bi * BI, j0 = bj * BJ, k0 = bk * (2 * BK);
    const int xg0 = i0 - HL, yg0 = j0 - HL;
    const int zg0A = k0 - HL, zg0B = k0 + BK - HL;

    // chunk0 loads (all threads, 1 group of 4 z-consecutive voxels)
    const int kgA = (t & 7) * 4, cjA = (t >> 3) & 7, ciA = t >> 6;
    const int iA = i0 + ciA, jA = j0 + cjA, kA = k0 + kgA;
    const int offA = iA * WD + jA * Dd + kA;
    const float4 sA  = *reinterpret_cast<const float4*>(src + offA);
    const float4 xA  = *reinterpret_cast<const float4*>(flow + offA);
    const float4 yA  = *reinterpret_cast<const float4*>(flow + N + offA);
    const float4 zA  = *reinterpret_cast<const float4*>(flow + 2 * N + offA);

    // chunk1 prefetch (threads 0-255, 2 groups each) — in flight during zero+P1
    float4 sB0, xB0, yB0, zB0, sB1, xB1, yB1, zB1;
    int iB0, jB0, kB0, iB1, jB1, kB1;
    if (t < 256) {
        {
            const int g = t;
            const int kg = (g & 7) * 4, cj = (g >> 3) & 7, ci = g >> 6;
            iB0 = i0 + ci; jB0 = j0 + cj; kB0 = k0 + BK + kg;
            const int off = iB0 * WD + jB0 * Dd + kB0;
            sB0 = *reinterpret_cast<const float4*>(src + off);
            xB0 = *reinterpret_cast<const float4*>(flow + off);
            yB0 = *reinterpret_cast<const float4*>(flow + N + off);
            zB0 = *reinterpret_cast<const float4*>(flow + 2 * N + off);
        }
        {
            const int g = t + 256;
            const int kg = (g & 7) * 4, cj = (g >> 3) & 7, ci = g >> 6;
            iB1 = i0 + ci; jB1 = j0 + cj; kB1 = k0 + BK + kg;
            const int off = iB1 * WD + jB1 * Dd + kB1;
            sB1 = *reinterpret_cast<const float4*>(src + off);
            xB1 = *reinterpret_cast<const float4*>(flow + off);
            yB1 = *reinterpret_cast<const float4*>(flow + N + off);
            zB1 = *reinterpret_cast<const float4*>(flow + 2 * N + off);
        }
    }

    // zero both buffers (9240 u64 = 4620 float4)
    {
        const float4 z4 = make_float4(0.f, 0.f, 0.f, 0.f);
        float4* b4 = reinterpret_cast<float4*>(&bins[0][0]);
        for (int c = t; c < 2 * TBINS / 2; c += 512) b4[c] = z4;
    }
    __syncthreads();

    // P1: all waves scatter chunk0 -> binsA
    scatter4(sA, xA, yA, zA, iA, jA, kA, xg0, yg0, zg0A, &bins[0][0], out);
    __syncthreads();

    // P2: waves 0-3 scatter chunk1 -> binsB  ||  waves 4-7 flush binsA
    if (t < 256) {
        scatter4(sB0, xB0, yB0, zB0, iB0, jB0, kB0, xg0, yg0, zg0B, &bins[1][0], out);
        scatter4(sB1, xB1, yB1, zB1, iB1, jB1, kB1, xg0, yg0, zg0B, &bins[1][0], out);
    } else {
        flush_bins(&bins[0][0], out, xg0, yg0, zg0A, t - 256, 256);
    }
    __syncthreads();

    // P3: all waves flush binsB
    flush_bins(&bins[1][0], out, xg0, yg0, zg0B, t, 512);
}

extern "C" void kernel_launch(void* const* d_in, const int* in_sizes, int n_in,
                              void* d_out, int out_size, void* d_ws, size_t ws_size,
                              hipStream_t stream) {
    const float* src  = (const float*)d_in[0];
    const float* flow = (const float*)d_in[1];
    float* out = (float*)d_out;

    // Harness poisons d_out once and never re-poisons between replays: zero it every call.
    hipMemsetAsync(out, 0, (size_t)N * sizeof(float), stream);

    const dim3 block(512);
    const dim3 grid(Dd / (2 * BK), W / BJ, H / BI);  // (3, 24, 24) = 1728 blocks
    splat_pipe_kernel<<<grid, block, 0, stream>>>(src, flow, out);
}